// Round 6
// baseline (673.605 us; speedup 1.0000x reference)
//
#include <hip/hip_runtime.h>

#define N_NODES 50000
#define N_EDGES 800000
#define IN_DIM 96
#define OUT_DIM 96
#define EDGE_DIM 32
#define BN_EPS 1e-5f

// ws layout (4-byte units):
//   [0 .. 4800000)          h buffer (new path: x+aggr; old path: aggr) -> reused as h2
//   [4800000 .. 4800192)    BN stats (sum, sumsq)
//   [4800192]               edge_index-dtype flag (1 = int64)
//   [4800256 .. 4850256)    counts  (50000 int)
//   [4850256 .. 4900257)    rowptr  (50001 int)
//   [4900260 .. 4950260)    cursor  (50000 int)
//   [4950272 .. 6550272)    eidx    (800000 int2)
#define OFF_STATS  4800000
#define OFF_FLAG   4800192
#define OFF_COUNTS 4800256
#define OFF_ROWPTR 4850256
#define OFF_CURSOR 4900260
#define OFF_EIDX   4950272
#define WS_REQ_NEW ((size_t)6550272 * 4)
#define WS_REQ_OLD ((size_t)(OFF_FLAG + 64) * 4)

// ---------------------------------------------------------------------------
// Kernel 0: detect edge_index storage width (int64 vs int32). int64 data with
// values < 50000 has every odd int32 word == 0.
// ---------------------------------------------------------------------------
__global__ void detect_kernel(const int* __restrict__ ei, int* __restrict__ flag) {
    __shared__ int any_nonzero;
    if (threadIdx.x == 0) any_nonzero = 0;
    __syncthreads();
    int nz = 0;
    for (int q = 0; q < 64; ++q) {
        int p = 1 + 2 * (threadIdx.x * 64 + q) * 48;  // odd, < 1,572,800
        if (ei[p] != 0) nz = 1;
    }
    if (nz) atomicOr(&any_nonzero, 1);
    __syncthreads();
    if (threadIdx.x == 0) *flag = any_nonzero ? 0 : 1;
}

__device__ __forceinline__ void load_edge(const int* __restrict__ ei, int e,
                                          int is64, int& s, int& d) {
    if (is64) { s = ei[2 * e]; d = ei[2 * N_EDGES + 2 * e]; }
    else      { s = ei[e];     d = ei[N_EDGES + e]; }
}

// ---------------------------------------------------------------------------
// CSR build: hist -> scan -> scatter
// ---------------------------------------------------------------------------
__global__ __launch_bounds__(256) void hist_kernel(const int* __restrict__ ei,
                                                   int* __restrict__ counts,
                                                   const int* __restrict__ flag) {
    const int is64 = *flag;
    for (int e = blockIdx.x * blockDim.x + threadIdx.x; e < N_EDGES;
         e += gridDim.x * blockDim.x) {
        int s, d;
        load_edge(ei, e, is64, s, d);
        if (s >= 0 && s < N_NODES && d >= 0 && d < N_NODES)
            atomicAdd(&counts[d], 1);
    }
}

#define SCAN_T 1024
#define SCAN_C 49  // 1024*49 = 50176 >= 50000
__global__ __launch_bounds__(SCAN_T) void scan_kernel(
    const int* __restrict__ counts, int* __restrict__ rowptr,
    int* __restrict__ cursor) {
    __shared__ int ps[SCAN_T];
    const int t = threadIdx.x;
    const int lo = t * SCAN_C;
    const int hi = (lo + SCAN_C < N_NODES) ? lo + SCAN_C : N_NODES;
    int s = 0;
    for (int i = lo; i < hi; ++i) s += counts[i];
    ps[t] = s;
    __syncthreads();
    for (int off = 1; off < SCAN_T; off <<= 1) {
        int v = ps[t];
        int u = (t >= off) ? ps[t - off] : 0;
        __syncthreads();
        ps[t] = v + u;
        __syncthreads();
    }
    int run = ps[t] - s;  // exclusive prefix
    for (int i = lo; i < hi; ++i) {
        rowptr[i] = run;
        cursor[i] = run;
        run += counts[i];
    }
    if (t == SCAN_T - 1) rowptr[N_NODES] = ps[SCAN_T - 1];
}

__global__ __launch_bounds__(256) void scatter_kernel(
    const int* __restrict__ ei, int* __restrict__ cursor,
    int2* __restrict__ eidx, const int* __restrict__ flag) {
    const int is64 = *flag;
    for (int e = blockIdx.x * blockDim.x + threadIdx.x; e < N_EDGES;
         e += gridDim.x * blockDim.x) {
        int s, d;
        load_edge(ei, e, is64, s, d);
        if (s >= 0 && s < N_NODES && d >= 0 && d < N_NODES) {
            int pos = atomicAdd(&cursor[d], 1);
            eidx[pos] = make_int2(s, e);
        }
    }
}

// ---------------------------------------------------------------------------
// Aggregate: ONE WAVE PER NODE. Lane j holds We columns j (and j+64 for
// lanes<32) in registers. Edge list is wave-uniform -> readfirstlane forces
// scalar/broadcast loads of (src,e) and the ea row. No LDS, no barriers, no
// atomics. Writes h = x + sum(relu(x[src] + ea@We + be)).
// ---------------------------------------------------------------------------
__global__ __launch_bounds__(256) void aggregate_kernel(
    const float* __restrict__ x, const float* __restrict__ ea,
    const float* __restrict__ We, const float* __restrict__ be,
    const int* __restrict__ rowptr, const int2* __restrict__ eidx,
    float* __restrict__ h) {
    const int lane = threadIdx.x & 63;
    const int wid = __builtin_amdgcn_readfirstlane(threadIdx.x >> 6);
    const int l32 = lane & 31;

    float w0[32], w1[32];
#pragma unroll
    for (int k = 0; k < 32; ++k) {
        w0[k] = We[k * 96 + lane];
        w1[k] = We[k * 96 + 64 + l32];
    }
    const float be0 = be[lane];
    const float be1 = be[64 + l32];

    const int nw = gridDim.x * 4;
    for (int n = blockIdx.x * 4 + wid; n < N_NODES; n += nw) {
        const int beg = rowptr[n];
        const int end = rowptr[n + 1];
        float a0 = 0.f, a1 = 0.f;
        for (int i = beg; i < end; ++i) {
            int2 pr = eidx[i];
            int s = __builtin_amdgcn_readfirstlane(pr.x);
            int e = __builtin_amdgcn_readfirstlane(pr.y);
            const float4* q4 = (const float4*)(ea + (size_t)e * EDGE_DIM);
            float4 Q[8];
#pragma unroll
            for (int r = 0; r < 8; ++r) Q[r] = q4[r];
            float d0 = be0, d1 = be1;
#pragma unroll
            for (int r = 0; r < 8; ++r) {
                d0 += Q[r].x * w0[4 * r + 0]; d1 += Q[r].x * w1[4 * r + 0];
                d0 += Q[r].y * w0[4 * r + 1]; d1 += Q[r].y * w1[4 * r + 1];
                d0 += Q[r].z * w0[4 * r + 2]; d1 += Q[r].z * w1[4 * r + 2];
                d0 += Q[r].w * w0[4 * r + 3]; d1 += Q[r].w * w1[4 * r + 3];
            }
            const float xa = x[(size_t)s * 96 + lane];
            const float xb = x[(size_t)s * 96 + 64 + l32];
            float m0 = xa + d0; m0 = m0 > 0.f ? m0 : 0.f;
            float m1 = xb + d1; m1 = m1 > 0.f ? m1 : 0.f;
            a0 += m0; a1 += m1;
        }
        const size_t b = (size_t)n * 96;
        h[b + lane] = x[b + lane] + a0;
        if (lane < 32) h[b + 64 + lane] = x[b + 64 + lane] + a1;
    }
}

// ---------------------------------------------------------------------------
// Fallback (small ws): atomic scatter-add edge kernel (R5 proven path).
// ---------------------------------------------------------------------------
#define ESLOTS 4
#define EBLOCK (ESLOTS * 96)
__global__ __launch_bounds__(EBLOCK) void edge_kernel(
    const float* __restrict__ x, const int* __restrict__ ei,
    const float* __restrict__ ea, const float* __restrict__ We,
    const float* __restrict__ be, float* __restrict__ aggr,
    const int* __restrict__ flag) {
    const int tid = threadIdx.x;
    const int slot = tid / 96;
    const int j = tid - slot * 96;
    const int is64 = *flag;
    float w[EDGE_DIM];
#pragma unroll
    for (int k = 0; k < EDGE_DIM; ++k) w[k] = We[k * 96 + j];
    const float bej = be[j];
    __shared__ float ea_s[ESLOTS][EDGE_DIM];
    for (long e0 = (long)blockIdx.x * ESLOTS; e0 < N_EDGES;
         e0 += (long)gridDim.x * ESLOTS) {
        const int e = (int)e0 + slot;
        const bool valid = (e < N_EDGES);
        if (valid && j < EDGE_DIM) ea_s[slot][j] = ea[e * EDGE_DIM + j];
        __syncthreads();
        if (valid) {
            float acc = bej;
#pragma unroll
            for (int k = 0; k < EDGE_DIM; ++k) acc += ea_s[slot][k] * w[k];
            int s, d;
            load_edge(ei, e, is64, s, d);
            if (s >= 0 && s < N_NODES && d >= 0 && d < N_NODES) {
                float m = acc + x[s * 96 + j];
                m = m > 0.f ? m : 0.f;
                atomicAdd(&aggr[d * 96 + j], m);
            }
        }
        __syncthreads();
    }
}

// ---------------------------------------------------------------------------
// Node MLP (fp32). 32-node tile per block, 256 threads. buf = h (addx=0) or
// aggr (addx=1, fallback). Writes o back into the same buffer (disjoint rows
// per block; rows read to LDS first). BN partials -> global atomics.
// ---------------------------------------------------------------------------
__global__ __launch_bounds__(256) void mlp_kernel(
    const float* __restrict__ x, const float* buf, int addx,
    const float* __restrict__ W1g, const float* __restrict__ b1g,
    const float* __restrict__ W2g, const float* __restrict__ b2g,
    float* h2, float* __restrict__ stats) {
    __shared__ float Ws[96 * 96];
    __shared__ float hs[32][97];
    __shared__ float os[32][97];
    __shared__ float b1s[96], b2s[96];

    const int tid = threadIdx.x;
    const int n0 = blockIdx.x * 32;

    for (int i = tid; i < 96 * 96; i += 256) Ws[i] = W1g[i];
    if (tid < 96) {
        b1s[tid] = b1g[tid];
        b2s[tid] = b2g[tid];
    }
    for (int i = tid; i < 32 * 96; i += 256) {
        int n = i / 96, k = i - n * 96;
        float v = 0.f;
        if (n0 + n < N_NODES) {
            int idx = (n0 + n) * 96 + k;
            v = buf[idx];
            if (addx) v += x[idx];
        }
        hs[n][k] = v;
    }
    __syncthreads();

    const int n = tid >> 3;
    const int jg = tid & 7;
    float acc[12];

#pragma unroll
    for (int m = 0; m < 12; ++m) acc[m] = b1s[jg * 12 + m];
    for (int k = 0; k < 96; ++k) {
        float hv = hs[n][k];
#pragma unroll
        for (int m = 0; m < 12; ++m) acc[m] += hv * Ws[k * 96 + jg * 12 + m];
    }
#pragma unroll
    for (int m = 0; m < 12; ++m)
        os[n][jg * 12 + m] = acc[m] > 0.f ? acc[m] : 0.f;
    __syncthreads();

    for (int i = tid; i < 96 * 96; i += 256) Ws[i] = W2g[i];
    __syncthreads();

#pragma unroll
    for (int m = 0; m < 12; ++m) acc[m] = b2s[jg * 12 + m];
    for (int k = 0; k < 96; ++k) {
        float hv = os[n][k];
#pragma unroll
        for (int m = 0; m < 12; ++m) acc[m] += hv * Ws[k * 96 + jg * 12 + m];
    }
#pragma unroll
    for (int m = 0; m < 12; ++m) hs[n][jg * 12 + m] = acc[m];
    __syncthreads();

    for (int i = tid; i < 32 * 96; i += 256) {
        int nn = i / 96, k = i - nn * 96;
        if (n0 + nn < N_NODES) h2[(n0 + nn) * 96 + k] = hs[nn][k];
    }
    if (tid < 96) {
        float s = 0.f, s2 = 0.f;
        int nmax = N_NODES - n0;
        if (nmax > 32) nmax = 32;
        for (int nn = 0; nn < nmax; ++nn) {
            float v = hs[nn][tid];
            s += v;
            s2 += v * v;
        }
        atomicAdd(&stats[tid], s);
        atomicAdd(&stats[96 + tid], s2);
    }
}

// ---------------------------------------------------------------------------
// BN finalize + affine + ReLU -> fp32 out.
// ---------------------------------------------------------------------------
__global__ __launch_bounds__(256) void bn_kernel(
    const float* __restrict__ h2, const float* __restrict__ stats,
    const float* __restrict__ gamma, const float* __restrict__ beta,
    float* __restrict__ out) {
    __shared__ float sc[96], sh[96];
    const int tid = threadIdx.x;
    if (tid < 96) {
        const float inv_n = 1.f / (float)N_NODES;
        float mean = stats[tid] * inv_n;
        float var = stats[96 + tid] * inv_n - mean * mean;
        var = var > 0.f ? var : 0.f;
        float s = gamma[tid] * rsqrtf(var + BN_EPS);
        sc[tid] = s;
        sh[tid] = beta[tid] - mean * s;
    }
    __syncthreads();
    const int total = N_NODES * 96;
    for (int i = blockIdx.x * blockDim.x + tid; i < total;
         i += gridDim.x * blockDim.x) {
        int j = i % 96;
        float v = h2[i] * sc[j] + sh[j];
        out[i] = v > 0.f ? v : 0.f;
    }
}

// ---------------------------------------------------------------------------
extern "C" void kernel_launch(void* const* d_in, const int* in_sizes, int n_in,
                              void* d_out, int out_size, void* d_ws,
                              size_t ws_size, hipStream_t stream) {
    const float* x     = (const float*)d_in[0];
    const int*   ei    = (const int*)d_in[1];
    const float* ea    = (const float*)d_in[2];
    const float* We    = (const float*)d_in[3];
    const float* be    = (const float*)d_in[4];
    const float* W1    = (const float*)d_in[5];
    const float* b1    = (const float*)d_in[6];
    const float* W2    = (const float*)d_in[7];
    const float* b2    = (const float*)d_in[8];
    const float* gamma = (const float*)d_in[9];
    const float* beta  = (const float*)d_in[10];
    float* out = (float*)d_out;

    float* ws     = (float*)d_ws;
    float* hbuf   = ws;                       // 4.8M floats (h / aggr / h2)
    float* stats  = ws + OFF_STATS;
    int*   flag   = (int*)(ws + OFF_FLAG);
    int*   counts = (int*)(ws + OFF_COUNTS);
    int*   rowptr = (int*)(ws + OFF_ROWPTR);
    int*   cursor = (int*)(ws + OFF_CURSOR);
    int2*  eidx   = (int2*)(ws + OFF_EIDX);

    if (ws_size >= WS_REQ_NEW) {
        // zero stats + flag + counts (201 KB); h fully overwritten by aggregate
        hipMemsetAsync((void*)stats, 0,
                       (size_t)(OFF_COUNTS + N_NODES - OFF_STATS) * 4, stream);
        detect_kernel<<<1, 256, 0, stream>>>(ei, flag);
        hist_kernel<<<1024, 256, 0, stream>>>(ei, counts, flag);
        scan_kernel<<<1, SCAN_T, 0, stream>>>(counts, rowptr, cursor);
        scatter_kernel<<<1024, 256, 0, stream>>>(ei, cursor, eidx, flag);
        aggregate_kernel<<<2048, 256, 0, stream>>>(x, ea, We, be, rowptr, eidx,
                                                   hbuf);
        mlp_kernel<<<(N_NODES + 31) / 32, 256, 0, stream>>>(
            x, hbuf, /*addx=*/0, W1, b1, W2, b2, /*h2=*/hbuf, stats);
    } else {
        // fallback: atomic path (R5), zero h+stats+flag
        size_t zbytes = WS_REQ_OLD;
        if (zbytes > ws_size) zbytes = ws_size;
        hipMemsetAsync(d_ws, 0, zbytes, stream);
        detect_kernel<<<1, 256, 0, stream>>>(ei, flag);
        edge_kernel<<<2048, EBLOCK, 0, stream>>>(x, ei, ea, We, be, hbuf, flag);
        mlp_kernel<<<(N_NODES + 31) / 32, 256, 0, stream>>>(
            x, hbuf, /*addx=*/1, W1, b1, W2, b2, /*h2=*/hbuf, stats);
    }
    bn_kernel<<<512, 256, 0, stream>>>(hbuf, stats, gamma, beta, out);
}